// Round 15
// baseline (101.768 us; speedup 1.0000x reference)
//
#include <hip/hip_runtime.h>
#include <hip/hip_bf16.h>
#include <hip/hip_fp8.h>

typedef __bf16 bf16_t;
typedef bf16_t bf16x4 __attribute__((ext_vector_type(4)));
typedef bf16_t bf16x8 __attribute__((ext_vector_type(8)));
typedef float  f32x4  __attribute__((ext_vector_type(4)));

#define B_  8
#define L_  2048
#define H_  1024
#define LV_ 256

typedef const __attribute__((address_space(1))) void* gptr_as1;
typedef __attribute__((address_space(3))) void* lptr_as3;

__device__ __forceinline__ void gload_lds16(void* lds_base, const void* gsrc) {
  __builtin_amdgcn_global_load_lds((gptr_as1)gsrc, (lptr_as3)lds_base, 16, 0, 0);
}

__device__ __forceinline__ unsigned char to_fp8(float x) {
  return __hip_fp8_e4m3(x).__x;
}

// ==== K1: vpool(64) | WtT transpose(256) | cbb(256) | zero-u(8) ============
__global__ __launch_bounds__(256) void prep1(const float* __restrict__ vf,
                                             const float* __restrict__ Wt,
                                             const float* __restrict__ Wg,
                                             const float* __restrict__ bt,
                                             const float* __restrict__ bg,
                                             float* __restrict__ pooled,
                                             bf16_t* __restrict__ WtT,
                                             float* __restrict__ cbb,
                                             float* __restrict__ u) {
  __shared__ __align__(16) char shm[16640];
  int bid = blockIdx.x;
  int t = threadIdx.x;
  if (bid < 64) {                       // vision mean-pool
    float* part = (float*)shm;
    int b = bid >> 3, hc = bid & 7;
    int h = hc * 128 + (t & 127);
    int kh = t >> 7;
    const float* p = vf + (long)b * (LV_ * H_) + (long)kh * 128 * H_ + h;
    float s = 0.f;
    #pragma unroll 4
    for (int k = 0; k < 128; ++k) s += p[k * H_];
    part[t] = s;
    __syncthreads();
    if (t < 128)
      pooled[b * H_ + hc * 128 + t] = (part[t] + part[t + 128]) * (1.f / 256.f);
  } else if (bid < 320) {               // Wt transpose-convert -> bf16
    float (*tile)[65] = (float(*)[65])shm;
    int lb = bid - 64;
    int hr = (lb >> 4) * 64;
    int ec = (lb & 15) * 64;
    int lr = t >> 4, lc = t & 15;
    #pragma unroll
    for (int rr = 0; rr < 4; ++rr) {
      int r = rr * 16 + lr;
      float4 v = *(const float4*)(Wt + (long)(hr + r) * H_ + ec + lc * 4);
      tile[r][lc * 4 + 0] = v.x; tile[r][lc * 4 + 1] = v.y;
      tile[r][lc * 4 + 2] = v.z; tile[r][lc * 4 + 3] = v.w;
    }
    __syncthreads();
    #pragma unroll
    for (int rr = 0; rr < 4; ++rr) {
      int er = rr * 16 + lr;
      bf16x4 o = { (bf16_t)tile[lc * 4 + 0][er], (bf16_t)tile[lc * 4 + 1][er],
                   (bf16_t)tile[lc * 4 + 2][er], (bf16_t)tile[lc * 4 + 3][er] };
      *(bf16x4*)(WtT + (long)(ec + er) * H_ + hr + lc * 4) = o;
    }
  } else if (bid < 576) {               // cbb = Wg[:, :H] @ bt + bg
    int lb = bid - 320;
    int wid = t >> 6, lane = t & 63;
    int o = lb * 4 + wid;
    const float* wr = Wg + (long)o * 2048;
    float acc = 0.f;
    for (int j = 0; j < 16; ++j) acc += wr[lane + 64 * j] * bt[lane + 64 * j];
    for (int off = 32; off; off >>= 1) acc += __shfl_down(acc, off);
    if (lane == 0) cbb[o] = acc + bg[o];
  } else {                              // zero u (for K3 atomics)
    int z = bid - 576;
    *(float4*)(u + z * 1024 + t * 4) = (float4){0.f, 0.f, 0.f, 0.f};
  }
}

// ------- out[b][o] = sum_h x[b][h]*W[o*ldw+woff+h] (+bias), 8 batches ------
__global__ void matvec8(const float* __restrict__ W, int ldw, int woff,
                        const float* __restrict__ x,
                        const float* __restrict__ bias,
                        float* __restrict__ out) {
  int wid = threadIdx.x >> 6, lane = threadIdx.x & 63;
  int o = blockIdx.x * 4 + wid;
  const float* wr = W + (long)o * ldw + woff;
  float acc[B_];
  #pragma unroll
  for (int b = 0; b < B_; ++b) acc[b] = 0.f;
  for (int j = 0; j < 16; ++j) {
    float w = wr[lane + 64 * j];
    #pragma unroll
    for (int b = 0; b < B_; ++b) acc[b] += w * x[b * H_ + lane + 64 * j];
  }
  #pragma unroll
  for (int b = 0; b < B_; ++b)
    for (int off = 32; off; off >>= 1) acc[b] += __shfl_down(acc[b], off);
  if (lane == 0) {
    float bb = bias ? bias[o] : 0.f;
    #pragma unroll
    for (int b = 0; b < B_; ++b) out[b * H_ + o] = acc[b] + bb;
  }
}

// ==== K3: gv(256) | u += Wt^T vp partials via atomics(256) =================
__global__ __launch_bounds__(256) void prep3(const float* __restrict__ Wg,
                                             const float* __restrict__ Wt,
                                             const float* __restrict__ vp,
                                             float* __restrict__ gv,
                                             float* __restrict__ u) {
  int bid = blockIdx.x;
  int t = threadIdx.x;
  if (bid < 256) {                      // gv = Wg[:, H:] @ vp
    int wid = t >> 6, lane = t & 63;
    int o = bid * 4 + wid;
    const float* wr = Wg + (long)o * 2048 + 1024;
    float acc[B_];
    #pragma unroll
    for (int b = 0; b < B_; ++b) acc[b] = 0.f;
    for (int j = 0; j < 16; ++j) {
      float w = wr[lane + 64 * j];
      #pragma unroll
      for (int b = 0; b < B_; ++b) acc[b] += w * vp[b * H_ + lane + 64 * j];
    }
    #pragma unroll
    for (int b = 0; b < B_; ++b)
      for (int off = 32; off; off >>= 1) acc[b] += __shfl_down(acc[b], off);
    if (lane == 0) {
      #pragma unroll
      for (int b = 0; b < B_; ++b) gv[b * H_ + o] = acc[b];
    }
  } else {                              // u[b][e] += sum_{o in chunk} Wt[o][e]*vp[b][o]
    int lb = bid - 256;                 // eb(4) x oc(64)
    int e = (lb & 3) * 256 + t;
    int oc = lb >> 2;
    float a[B_];
    #pragma unroll
    for (int b = 0; b < B_; ++b) a[b] = 0.f;
    #pragma unroll
    for (int i = 0; i < 16; ++i) {
      int o = oc * 16 + i;
      float w = Wt[(long)o * H_ + e];
      #pragma unroll
      for (int b = 0; b < B_; ++b) a[b] += w * vp[b * H_ + o];
    }
    #pragma unroll
    for (int b = 0; b < B_; ++b) atomicAdd(u + b * 1024 + e, a[b]);
  }
}

// ==== K4: [0,1024) text->fp8 frag-pack + agreement; [1024,1280) Wc8p GEMM ==
// kb-major packed layouts (wave-private contiguous DMA in gemm_ln):
//  t8p : chunk(mb_g, kb) at (mb_g>>2)*65536 + kb*2048 + (mb_g&3)*512
//  Wc8p: chunk(nb, kb)  at (nb>>3)*131072 + kb*4096 + (nb&7)*512
// Intra-chunk byte order: lane=(row&15)|(((col>>3)&3)<<4), byte=col&7.
__global__ __launch_bounds__(256) void cvt_wc(const float* __restrict__ text,
                                              const float* __restrict__ u,
                                              const float* __restrict__ Wg,
                                              const bf16_t* __restrict__ Bt,
                                              unsigned char* __restrict__ t8p,
                                              float* __restrict__ agr,
                                              unsigned char* __restrict__ Cw8) {
  __shared__ __align__(16) char shm[32800];
  int bid = blockIdx.x;
  int t = threadIdx.x;
  if (bid < 1024) {
    unsigned char (*q8)[1032] = (unsigned char(*)[1032])shm;  // +8B row pad
    float (*dred)[16] = (float(*)[16])(shm + 16512);
    int b = bid >> 7;                        // 128 blocks per batch
    int wid = t >> 6, lane = t & 63;
    const float4* trow = (const float4*)(text + (long)bid * (16 * H_));
    float4 uu = ((const float4*)(u + b * H_))[t];
    #pragma unroll 4
    for (int i = 0; i < 16; ++i) {           // i = row within 16-row block
      float4 v = trow[i * 256 + t];          // coalesced
      float d = v.x * uu.x + v.y * uu.y + v.z * uu.z + v.w * uu.w;
      for (int off = 32; off; off >>= 1) d += __shfl_down(d, off);
      if (!lane) dred[wid][i] = d;
      uchar4 q = { to_fp8(v.x), to_fp8(v.y), to_fp8(v.z), to_fp8(v.w) };
      *(uchar4*)&q8[i][t * 4] = q;
    }
    __syncthreads();
    if (t < 16)
      agr[bid * 16 + t] = dred[0][t] + dred[1][t] + dred[2][t] + dred[3][t];
    unsigned char* dst = t8p + (long)(bid >> 2) * 65536 + (bid & 3) * 512;
    #pragma unroll
    for (int c = 0; c < 8; ++c) {
      int kb = wid * 8 + c;
      uint2 r = *(const uint2*)&q8[lane & 15][kb * 32 + (lane >> 4) * 8];
      *(uint2*)(dst + kb * 2048 + lane * 8) = r;    // coalesced 512B/wave
    }
    return;
  }
  // ---- Wc8p = frag-packed fp8(16 * Wg[:, :H] @ WtT) ----
  const int tid = t;
  const int wid = tid >> 6, lane = tid & 63;
  const int fr = lane & 15, fkb = (lane >> 4) * 16, fq = (lane >> 4) * 4;
  const int wm = wid >> 1, wn = wid & 1;
  const int lb = bid - 1024;
  const int tm = lb & 15, tn = lb >> 4;
  const int m0 = tm * 64, n0 = tn * 64;

  char* ldsA = shm;                     // [2][16384]

  const int d0 = tid * 16;
  const int p  = d0 ^ (((d0 >> 7) & 7) << 4);
  const int rS = p >> 7, cS = (p & 127) >> 1;

  const int swz = (fr & 7) << 4;
  const int e0 = fkb ^ swz;
  const int e1 = (64 + fkb) ^ swz;

  auto stage = [&](int tt) {
    char* base = ldsA + (tt & 1) * 16384;
    gload_lds16(base + 8192 + d0,        Bt + (long)(n0 + rS) * H_ + tt * 64 + cS);
    gload_lds16(base + 8192 + 4096 + d0, Bt + (long)(n0 + 32 + rS) * H_ + tt * 64 + cS);
    const float* a0 = Wg + (long)(m0 + rS) * 2048 + tt * 64 + cS;
    const float* a1 = Wg + (long)(m0 + 32 + rS) * 2048 + tt * 64 + cS;
    float4 x0 = *(const float4*)a0, x1 = *(const float4*)(a0 + 4);
    float4 y0 = *(const float4*)a1, y1 = *(const float4*)(a1 + 4);
    bf16x8 bx = { (bf16_t)x0.x, (bf16_t)x0.y, (bf16_t)x0.z, (bf16_t)x0.w,
                  (bf16_t)x1.x, (bf16_t)x1.y, (bf16_t)x1.z, (bf16_t)x1.w };
    bf16x8 by = { (bf16_t)y0.x, (bf16_t)y0.y, (bf16_t)y0.z, (bf16_t)y0.w,
                  (bf16_t)y1.x, (bf16_t)y1.y, (bf16_t)y1.z, (bf16_t)y1.w };
    *(bf16x8*)(base + d0) = bx;
    *(bf16x8*)(base + 4096 + d0) = by;
  };

  f32x4 acc[2][2];
  #pragma unroll
  for (int m = 0; m < 2; ++m)
    #pragma unroll
    for (int n = 0; n < 2; ++n) acc[m][n] = (f32x4){0.f, 0.f, 0.f, 0.f};

  stage(0);
  __syncthreads();
  for (int tt = 0; tt < 16; ++tt) {
    if (tt + 1 < 16) stage(tt + 1);
    char* buf = ldsA + (tt & 1) * 16384;
    char* AR = buf + (wm * 32 + fr) * 128;
    char* BR = buf + 8192 + (wn * 32 + fr) * 128;
    bf16x8 a[2][2], b[2][2];
    #pragma unroll
    for (int m = 0; m < 2; ++m) {
      a[m][0] = *(const bf16x8*)(AR + m * 2048 + e0);
      a[m][1] = *(const bf16x8*)(AR + m * 2048 + e1);
      b[m][0] = *(const bf16x8*)(BR + m * 2048 + e0);
      b[m][1] = *(const bf16x8*)(BR + m * 2048 + e1);
    }
    #pragma unroll
    for (int m = 0; m < 2; ++m)
      #pragma unroll
      for (int n = 0; n < 2; ++n) {
        acc[m][n] = __builtin_amdgcn_mfma_f32_16x16x32_bf16(a[m][0], b[n][0], acc[m][n], 0, 0, 0);
        acc[m][n] = __builtin_amdgcn_mfma_f32_16x16x32_bf16(a[m][1], b[n][1], acc[m][n], 0, 0, 0);
      }
    __syncthreads();
  }
  #pragma unroll
  for (int m = 0; m < 2; ++m)
    #pragma unroll
    for (int r_ = 0; r_ < 4; ++r_) {
      int row = m0 + wm * 32 + m * 16 + fq + r_;
      #pragma unroll
      for (int n = 0; n < 2; ++n) {
        int col = n0 + wn * 32 + n * 16 + fr;
        Cw8[(long)(row >> 7) * 131072 + (col >> 5) * 4096 + ((row >> 4) & 7) * 512
            + ((row & 15) + (((col >> 3) & 3) << 4)) * 8 + (col & 7)]
          = to_fp8(acc[m][n][r_] * 16.f);   // x16 into e4m3 normal range
      }
    }
}

// ====== full-row fp8 GEMM + softmax + gate/residual + LayerNorm ============
// R12 core (verified 49.5us) + NEW: text L3-prefetch during the K-loop.
// The loop phase leaves HBM ~idle (0.6 TB/s) while the epilogue is
// HBM-bound on the 64MB text read. Each KITER issues ONE extra gload_lds16
// per thread (8KB/block/tile, 31 tiles = 248KB of the block's 256KB text)
// into a dummy 8KB LDS scratch -- data unused, side effect = HBM->L2/L3
// fill; L3 working set ~145MB < 256MB so it survives to the epilogue.
// vmcnt: prefetch issued AFTER each tile's wait, so steady queue at the
// wait = [pf(t-1), stage(t+1)x6] -> WN=7 for t>=1 (t=0: 6; t=31: 0, no pf).
#define BOFF 16777216   // Wc8p offset from t8p base
__global__ __launch_bounds__(512, 2)
void gemm_ln(const unsigned char* __restrict__ AB,
             const float* __restrict__ textf,
             const float* __restrict__ cbb, const float* __restrict__ agrb,
             const float* __restrict__ gvb, const float* __restrict__ vpb,
             const float* __restrict__ gamma, const float* __restrict__ beta,
             float* __restrict__ out) {
  extern __shared__ __align__(16) char dlds[];
  // wave w loop bufs: [w*12288, +12288) = 2 x {A 2K, B 4K}
  // params @98304 (20KB); red @118784; rvA @118848; dummy pf @119296 (8KB);
  // epilogue transpose tile @0 (reuses loop bufs).
  const int tid  = threadIdx.x;
  const int w    = tid >> 6;
  const int lane = tid & 63;
  const int fr   = lane & 15;
  const int fq   = (lane >> 4) * 4;
  const int bid  = blockIdx.x;
  const long m0  = (long)bid * 64;
  const int bat  = (int)(m0 >> 11);

  // ---- prologue: per-batch softmax over 2048 agr values ----
  {
    float* red = (float*)(dlds + 118784);
    float* rvA = (float*)(dlds + 118848);
    float4 av = *(const float4*)(agrb + (long)bat * 2048 + tid * 4);
    float mloc = fmaxf(fmaxf(av.x, av.y), fmaxf(av.z, av.w)) * 2.f;
    #pragma unroll
    for (int off = 32; off; off >>= 1) mloc = fmaxf(mloc, __shfl_xor(mloc, off));
    if ((tid & 63) == 0) red[tid >> 6] = mloc;
    __syncthreads();
    float mx = red[0];
    #pragma unroll
    for (int i = 1; i < 8; ++i) mx = fmaxf(mx, red[i]);
    float sl = __expf(2.f * av.x - mx) + __expf(2.f * av.y - mx)
             + __expf(2.f * av.z - mx) + __expf(2.f * av.w - mx);
    #pragma unroll
    for (int off = 32; off; off >>= 1) sl += __shfl_xor(sl, off);
    __syncthreads();
    if ((tid & 63) == 0) red[tid >> 6] = sl;
    __syncthreads();
    float ssum = red[0] + red[1] + red[2] + red[3]
               + red[4] + red[5] + red[6] + red[7];
    if (tid < 64) rvA[tid] = __expf(2.f * agrb[m0 + tid] - mx) / ssum;
    __syncthreads();
  }

  // ---- stage per-column params into LDS (once; drained by tile-0 vmcnt) --
  {
    char* P = dlds + 98304;
    if (tid < 256) {
      gload_lds16(P + tid * 16,          cbb + tid * 4);
      gload_lds16(P + 8192 + tid * 16,   vpb + bat * H_ + tid * 4);
      gload_lds16(P + 16384 + tid * 16,  beta + tid * 4);
    } else {
      int t2 = tid - 256;
      gload_lds16(P + 4096 + t2 * 16,    gvb + bat * H_ + t2 * 4);
      gload_lds16(P + 12288 + t2 * 16,   gamma + t2 * 4);
    }
  }

  // wave-private staging pointers (kb-major packed layouts)
  const unsigned char* aSrc = AB + (long)bid * 65536 + lane * 16;
  const unsigned char* bSrc = AB + BOFF + (long)w * 131072 + lane * 16;
  char* const wBase = dlds + w * 12288;
  // text prefetch: chunk t = bytes [t*8192,(t+1)*8192) of block's text
  const unsigned char* tPre = (const unsigned char*)textf + m0 * 4096 + tid * 16;
  char* const pfDst = dlds + 119296 + tid * 16;

  f32x4 acc[4][8];
  #pragma unroll
  for (int m = 0; m < 4; ++m)
    #pragma unroll
    for (int n = 0; n < 8; ++n) acc[m][n] = (f32x4){0.f, 0.f, 0.f, 0.f};

#define STAGE(t)                                                        \
  {                                                                     \
    char* D_ = wBase + ((t) & 1) * 6144 + lane * 16;                    \
    const unsigned char* As_ = aSrc + (t) * 2048;                       \
    gload_lds16(D_,        As_);                                        \
    gload_lds16(D_ + 1024, As_ + 1024);                                 \
    const unsigned char* Bs_ = bSrc + (t) * 4096;                       \
    _Pragma("unroll")                                                   \
    for (int r_ = 0; r_ < 4; ++r_)                                      \
      gload_lds16(D_ + 2048 + r_ * 1024, Bs_ + r_ * 1024);              \
  }
#define KITER(t, WN, PF)                                                \
  {                                                                     \
    asm volatile("s_waitcnt lgkmcnt(0)" ::: "memory");                  \
    __builtin_amdgcn_sched_barrier(0);                                  \
    if ((t) + 1 < 32) STAGE((t) + 1)                                    \
    asm volatile("s_waitcnt vmcnt(" #WN ")" ::: "memory");              \
    __builtin_amdgcn_sched_barrier(0);                                  \
    if (PF) gload_lds16(pfDst, tPre + (t) * 8192);                      \
    const char* R_ = wBase + ((t) & 1) * 6144 + lane * 8;               \
    long a_[4], b_[8];                                                  \
    _Pragma("unroll")                                                   \
    for (int m_ = 0; m_ < 4; ++m_)                                      \
      a_[m_] = *(const long*)(R_ + m_ * 512);                           \
    _Pragma("unroll")                                                   \
    for (int n_ = 0; n_ < 8; ++n_)                                      \
      b_[n_] = *(const long*)(R_ + 2048 + n_ * 512);                    \
    __builtin_amdgcn_s_setprio(1);                                      \
    _Pragma("unroll")                                                   \
    for (int m_ = 0; m_ < 4; ++m_)                                      \
      _Pragma("unroll")                                                 \
      for (int n_ = 0; n_ < 8; ++n_)                                    \
        acc[m_][n_] = __builtin_amdgcn_mfma_f32_16x16x32_fp8_fp8(       \
            a_[m_], b_[n_], acc[m_][n_], 0, 0, 0);                      \
    __builtin_amdgcn_s_setprio(0);                                      \
  }

  STAGE(0)

  KITER(0, 6, 1)
  KITER(1, 7, 1)  KITER(2, 7, 1)  KITER(3, 7, 1)  KITER(4, 7, 1)
  KITER(5, 7, 1)  KITER(6, 7, 1)  KITER(7, 7, 1)  KITER(8, 7, 1)
  KITER(9, 7, 1)  KITER(10, 7, 1) KITER(11, 7, 1) KITER(12, 7, 1)
  KITER(13, 7, 1) KITER(14, 7, 1) KITER(15, 7, 1) KITER(16, 7, 1)
  KITER(17, 7, 1) KITER(18, 7, 1) KITER(19, 7, 1) KITER(20, 7, 1)
  KITER(21, 7, 1) KITER(22, 7, 1) KITER(23, 7, 1) KITER(24, 7, 1)
  KITER(25, 7, 1) KITER(26, 7, 1) KITER(27, 7, 1) KITER(28, 7, 1)
  KITER(29, 7, 1) KITER(30, 7, 1)
  KITER(31, 0, 0)
#undef KITER
#undef STAGE

  // ---- epilogue: 4 passes of 16 rows; LDS transpose -> coalesced ----------
  const int lr = tid >> 5;              // local row 0..15
  const int jj = tid & 31;              // col-chunk owner
  char* P = dlds + 98304;
  const float* rvA = (const float*)(dlds + 118848);

  #pragma unroll
  for (int m = 0; m < 4; ++m) {
    __syncthreads();                    // converge; LDS loop bufs now free
    #pragma unroll
    for (int n = 0; n < 8; ++n) {
      #pragma unroll
      for (int r = 0; r < 4; ++r) {
        int rl = fq + r;
        int c  = (w * 128 + n * 16 + fr) ^ (((rl >> 2) & 3) << 4);
        *(float*)(dlds + rl * 4096 + c * 4) = acc[m][n][r];
      }
    }
    __syncthreads();
    long row = m0 + m * 16 + lr;
    float rv = rvA[m * 16 + lr];
    const float* tf = textf + row * H_;
    const int rot = ((lr >> 2) & 3) << 4;
    float s = 0.f, q = 0.f;
    #pragma unroll 2
    for (int k = 0; k < 8; ++k) {
      int c0 = k * 128 + jj * 4;        // coalesced: 32 lanes cover 128 cols
      char* slot = dlds + lr * 4096 + ((c0 ^ rot) * 4);
      f32x4 a4 = *(const f32x4*)slot;
      float4 t4  = *(const float4*)(tf + c0);
      f32x4 cb4 = *(const f32x4*)(P + c0 * 4);
      f32x4 gv4 = *(const f32x4*)(P + 4096 + c0 * 4);
      f32x4 vp4 = *(const f32x4*)(P + 8192 + c0 * 4);
      f32x4 f4;
      float gp, g;
      gp = a4[0] * 0.0625f + cb4[0] + rv * gv4[0];
      g = 1.f / (1.f + __expf(-gp));
      f4[0] = t4.x + g * rv * vp4[0];
      gp = a4[1] * 0.0625f + cb4[1] + rv * gv4[1];
      g = 1.f / (1.f + __expf(-gp));
      f4[1] = t4.y + g * rv * vp4[1];
      gp = a4[2] * 0.0625f + cb4[2] + rv * gv4[2];
      g = 1.f / (1.f + __expf(-gp));
      f4[2] = t4.z + g * rv * vp4[2];
      gp = a4[3] * 0.0625f + cb4[3] + rv * gv4[3];
      g = 1.f / (1.f + __expf(-gp));
      f4[3] = t4.w + g * rv * vp4[3];
      *(f32x4*)slot = f4;               // fused value back to same slot
      s += f4[0] + f4[1] + f4[2] + f4[3];
      q += f4[0] * f4[0] + f4[1] * f4[1] + f4[2] * f4[2] + f4[3] * f4[3];
    }
    #pragma unroll
    for (int off = 1; off < 32; off <<= 1) {   // row stats over its 32 lanes
      s += __shfl_xor(s, off);
      q += __shfl_xor(q, off);
    }
    float mu  = s * (1.f / H_);
    float var = q * (1.f / H_) - mu * mu;
    float inv = rsqrtf(var + 1e-5f);
    float* op = out + row * H_;
    #pragma unroll 2
    for (int k = 0; k < 8; ++k) {
      int c0 = k * 128 + jj * 4;
      f32x4 f4 = *(const f32x4*)(dlds + lr * 4096 + ((c0 ^ rot) * 4));
      f32x4 gg = *(const f32x4*)(P + 12288 + c0 * 4);
      f32x4 bb = *(const f32x4*)(P + 16384 + c0 * 4);
      float4 o4;
      o4.x = (f4[0] - mu) * inv * gg[0] + bb[0];
      o4.y = (f4[1] - mu) * inv * gg[1] + bb[1];
      o4.z = (f4[2] - mu) * inv * gg[2] + bb[2];
      o4.w = (f4[3] - mu) * inv * gg[3] + bb[3];
      *(float4*)(op + c0) = o4;
    }
  }
}

extern "C" void kernel_launch(void* const* d_in, const int* in_sizes, int n_in,
                              void* d_out, int out_size, void* d_ws, size_t ws_size,
                              hipStream_t stream) {
  const float* text  = (const float*)d_in[0];
  const float* vis   = (const float*)d_in[1];
  const float* Wt    = (const float*)d_in[2];
  const float* bt    = (const float*)d_in[3];
  const float* Wv    = (const float*)d_in[4];
  const float* bv    = (const float*)d_in[5];
  const float* Wg    = (const float*)d_in[6];
  const float* bg    = (const float*)d_in[7];
  const float* gamma = (const float*)d_in[8];
  const float* beta  = (const float*)d_in[9];
  float* out = (float*)d_out;

  char* ws = (char*)d_ws;
  unsigned char* t8p   = (unsigned char*)(ws);                    // 16 MiB (packed A)
  unsigned char* Wc8p  = (unsigned char*)(ws + (size_t)16777216); // 1 MiB (packed B)
  bf16_t* WtT_b = (bf16_t*)(ws + (size_t)17825792);               // 2 MiB
  float*  pooled = (float*)(ws + (size_t)19922944);               // 32 KiB
  float*  vp     = (float*)(ws + (size_t)19955712);               // 32 KiB
  float*  gv     = (float*)(ws + (size_t)19988480);               // 32 KiB
  float*  u      = (float*)(ws + (size_t)20021248);               // 32 KiB
  float*  cbb    = (float*)(ws + (size_t)20054016);               // 4 KiB
  float*  agr    = (float*)(ws + (size_t)20123648);               // 64 KiB

  static bool smem_set = false;
  if (!smem_set) {
    (void)hipFuncSetAttribute((const void*)gemm_ln,
                              hipFuncAttributeMaxDynamicSharedMemorySize, 127488);
    smem_set = true;
  }

  prep1<<<584, 256, 0, stream>>>(vis, Wt, Wg, bt, bg, pooled, WtT_b, cbb, u);
  matvec8<<<256, 256, 0, stream>>>(Wv, 1024, 0, pooled, bv, vp);  // vp
  prep3<<<512, 256, 0, stream>>>(Wg, Wt, vp, gv, u);              // gv + u
  cvt_wc<<<1280, 256, 0, stream>>>(text, u, Wg, WtT_b, t8p, agr, Wc8p);
  gemm_ln<<<256, 512, 127488, stream>>>(t8p, text, cbb, agr, gv, vp,
                                        gamma, beta, out);
}

// Round 16
// 99.520 us; speedup vs baseline: 1.0226x; 1.0226x over previous
//
#include <hip/hip_runtime.h>
#include <hip/hip_bf16.h>
#include <hip/hip_fp8.h>

typedef __bf16 bf16_t;
typedef bf16_t bf16x4 __attribute__((ext_vector_type(4)));
typedef bf16_t bf16x8 __attribute__((ext_vector_type(8)));
typedef float  f32x4  __attribute__((ext_vector_type(4)));

#define B_  8
#define L_  2048
#define H_  1024
#define LV_ 256

typedef const __attribute__((address_space(1))) void* gptr_as1;
typedef __attribute__((address_space(3))) void* lptr_as3;

__device__ __forceinline__ void gload_lds16(void* lds_base, const void* gsrc) {
  __builtin_amdgcn_global_load_lds((gptr_as1)gsrc, (lptr_as3)lds_base, 16, 0, 0);
}

__device__ __forceinline__ unsigned char to_fp8(float x) {
  return __hip_fp8_e4m3(x).__x;
}

// ==== K1: vpool(64) | WtT transpose(256) | cbb(256) | zero-u(8) ============
__global__ __launch_bounds__(256) void prep1(const float* __restrict__ vf,
                                             const float* __restrict__ Wt,
                                             const float* __restrict__ Wg,
                                             const float* __restrict__ bt,
                                             const float* __restrict__ bg,
                                             float* __restrict__ pooled,
                                             bf16_t* __restrict__ WtT,
                                             float* __restrict__ cbb,
                                             float* __restrict__ u) {
  __shared__ __align__(16) char shm[16640];
  int bid = blockIdx.x;
  int t = threadIdx.x;
  if (bid < 64) {                       // vision mean-pool
    float* part = (float*)shm;
    int b = bid >> 3, hc = bid & 7;
    int h = hc * 128 + (t & 127);
    int kh = t >> 7;
    const float* p = vf + (long)b * (LV_ * H_) + (long)kh * 128 * H_ + h;
    float s = 0.f;
    #pragma unroll 4
    for (int k = 0; k < 128; ++k) s += p[k * H_];
    part[t] = s;
    __syncthreads();
    if (t < 128)
      pooled[b * H_ + hc * 128 + t] = (part[t] + part[t + 128]) * (1.f / 256.f);
  } else if (bid < 320) {               // Wt transpose-convert -> bf16
    float (*tile)[65] = (float(*)[65])shm;
    int lb = bid - 64;
    int hr = (lb >> 4) * 64;
    int ec = (lb & 15) * 64;
    int lr = t >> 4, lc = t & 15;
    #pragma unroll
    for (int rr = 0; rr < 4; ++rr) {
      int r = rr * 16 + lr;
      float4 v = *(const float4*)(Wt + (long)(hr + r) * H_ + ec + lc * 4);
      tile[r][lc * 4 + 0] = v.x; tile[r][lc * 4 + 1] = v.y;
      tile[r][lc * 4 + 2] = v.z; tile[r][lc * 4 + 3] = v.w;
    }
    __syncthreads();
    #pragma unroll
    for (int rr = 0; rr < 4; ++rr) {
      int er = rr * 16 + lr;
      bf16x4 o = { (bf16_t)tile[lc * 4 + 0][er], (bf16_t)tile[lc * 4 + 1][er],
                   (bf16_t)tile[lc * 4 + 2][er], (bf16_t)tile[lc * 4 + 3][er] };
      *(bf16x4*)(WtT + (long)(ec + er) * H_ + hr + lc * 4) = o;
    }
  } else if (bid < 576) {               // cbb = Wg[:, :H] @ bt + bg
    int lb = bid - 320;
    int wid = t >> 6, lane = t & 63;
    int o = lb * 4 + wid;
    const float* wr = Wg + (long)o * 2048;
    float acc = 0.f;
    for (int j = 0; j < 16; ++j) acc += wr[lane + 64 * j] * bt[lane + 64 * j];
    for (int off = 32; off; off >>= 1) acc += __shfl_down(acc, off);
    if (lane == 0) cbb[o] = acc + bg[o];
  } else {                              // zero u (for K3 atomics)
    int z = bid - 576;
    *(float4*)(u + z * 1024 + t * 4) = (float4){0.f, 0.f, 0.f, 0.f};
  }
}

// ------- out[b][o] = sum_h x[b][h]*W[o*ldw+woff+h] (+bias), 8 batches ------
__global__ void matvec8(const float* __restrict__ W, int ldw, int woff,
                        const float* __restrict__ x,
                        const float* __restrict__ bias,
                        float* __restrict__ out) {
  int wid = threadIdx.x >> 6, lane = threadIdx.x & 63;
  int o = blockIdx.x * 4 + wid;
  const float* wr = W + (long)o * ldw + woff;
  float acc[B_];
  #pragma unroll
  for (int b = 0; b < B_; ++b) acc[b] = 0.f;
  for (int j = 0; j < 16; ++j) {
    float w = wr[lane + 64 * j];
    #pragma unroll
    for (int b = 0; b < B_; ++b) acc[b] += w * x[b * H_ + lane + 64 * j];
  }
  #pragma unroll
  for (int b = 0; b < B_; ++b)
    for (int off = 32; off; off >>= 1) acc[b] += __shfl_down(acc[b], off);
  if (lane == 0) {
    float bb = bias ? bias[o] : 0.f;
    #pragma unroll
    for (int b = 0; b < B_; ++b) out[b * H_ + o] = acc[b] + bb;
  }
}

// ==== K3: gv(256) | u += Wt^T vp partials via atomics(256) =================
__global__ __launch_bounds__(256) void prep3(const float* __restrict__ Wg,
                                             const float* __restrict__ Wt,
                                             const float* __restrict__ vp,
                                             float* __restrict__ gv,
                                             float* __restrict__ u) {
  int bid = blockIdx.x;
  int t = threadIdx.x;
  if (bid < 256) {                      // gv = Wg[:, H:] @ vp
    int wid = t >> 6, lane = t & 63;
    int o = bid * 4 + wid;
    const float* wr = Wg + (long)o * 2048 + 1024;
    float acc[B_];
    #pragma unroll
    for (int b = 0; b < B_; ++b) acc[b] = 0.f;
    for (int j = 0; j < 16; ++j) {
      float w = wr[lane + 64 * j];
      #pragma unroll
      for (int b = 0; b < B_; ++b) acc[b] += w * vp[b * H_ + lane + 64 * j];
    }
    #pragma unroll
    for (int b = 0; b < B_; ++b)
      for (int off = 32; off; off >>= 1) acc[b] += __shfl_down(acc[b], off);
    if (lane == 0) {
      #pragma unroll
      for (int b = 0; b < B_; ++b) gv[b * H_ + o] = acc[b];
    }
  } else {                              // u[b][e] += sum_{o in chunk} Wt[o][e]*vp[b][o]
    int lb = bid - 256;                 // eb(4) x oc(64)
    int e = (lb & 3) * 256 + t;
    int oc = lb >> 2;
    float a[B_];
    #pragma unroll
    for (int b = 0; b < B_; ++b) a[b] = 0.f;
    #pragma unroll
    for (int i = 0; i < 16; ++i) {
      int o = oc * 16 + i;
      float w = Wt[(long)o * H_ + e];
      #pragma unroll
      for (int b = 0; b < B_; ++b) a[b] += w * vp[b * H_ + o];
    }
    #pragma unroll
    for (int b = 0; b < B_; ++b) atomicAdd(u + b * 1024 + e, a[b]);
  }
}

// ==== K4: [0,1024) text->fp8 frag-pack + agreement; [1024,1280) Wc8p GEMM ==
// kb-major packed layouts (wave-private contiguous DMA in gemm_ln):
//  t8p : chunk(mb_g, kb) at (mb_g>>2)*65536 + kb*2048 + (mb_g&3)*512
//  Wc8p: chunk(nb, kb)  at (nb>>3)*131072 + kb*4096 + (nb&7)*512
// Intra-chunk byte order: lane=(row&15)|(((col>>3)&3)<<4), byte=col&7.
__global__ __launch_bounds__(256) void cvt_wc(const float* __restrict__ text,
                                              const float* __restrict__ u,
                                              const float* __restrict__ Wg,
                                              const bf16_t* __restrict__ Bt,
                                              unsigned char* __restrict__ t8p,
                                              float* __restrict__ agr,
                                              unsigned char* __restrict__ Cw8) {
  __shared__ __align__(16) char shm[32800];
  int bid = blockIdx.x;
  int t = threadIdx.x;
  if (bid < 1024) {
    unsigned char (*q8)[1032] = (unsigned char(*)[1032])shm;  // +8B row pad
    float (*dred)[16] = (float(*)[16])(shm + 16512);
    int b = bid >> 7;                        // 128 blocks per batch
    int wid = t >> 6, lane = t & 63;
    const float4* trow = (const float4*)(text + (long)bid * (16 * H_));
    float4 uu = ((const float4*)(u + b * H_))[t];
    #pragma unroll 4
    for (int i = 0; i < 16; ++i) {           // i = row within 16-row block
      float4 v = trow[i * 256 + t];          // coalesced
      float d = v.x * uu.x + v.y * uu.y + v.z * uu.z + v.w * uu.w;
      for (int off = 32; off; off >>= 1) d += __shfl_down(d, off);
      if (!lane) dred[wid][i] = d;
      uchar4 q = { to_fp8(v.x), to_fp8(v.y), to_fp8(v.z), to_fp8(v.w) };
      *(uchar4*)&q8[i][t * 4] = q;
    }
    __syncthreads();
    if (t < 16)
      agr[bid * 16 + t] = dred[0][t] + dred[1][t] + dred[2][t] + dred[3][t];
    unsigned char* dst = t8p + (long)(bid >> 2) * 65536 + (bid & 3) * 512;
    #pragma unroll
    for (int c = 0; c < 8; ++c) {
      int kb = wid * 8 + c;
      uint2 r = *(const uint2*)&q8[lane & 15][kb * 32 + (lane >> 4) * 8];
      *(uint2*)(dst + kb * 2048 + lane * 8) = r;    // coalesced 512B/wave
    }
    return;
  }
  // ---- Wc8p = frag-packed fp8(16 * Wg[:, :H] @ WtT) ----
  const int tid = t;
  const int wid = tid >> 6, lane = tid & 63;
  const int fr = lane & 15, fkb = (lane >> 4) * 16, fq = (lane >> 4) * 4;
  const int wm = wid >> 1, wn = wid & 1;
  const int lb = bid - 1024;
  const int tm = lb & 15, tn = lb >> 4;
  const int m0 = tm * 64, n0 = tn * 64;

  char* ldsA = shm;                     // [2][16384]

  const int d0 = tid * 16;
  const int p  = d0 ^ (((d0 >> 7) & 7) << 4);
  const int rS = p >> 7, cS = (p & 127) >> 1;

  const int swz = (fr & 7) << 4;
  const int e0 = fkb ^ swz;
  const int e1 = (64 + fkb) ^ swz;

  auto stage = [&](int tt) {
    char* base = ldsA + (tt & 1) * 16384;
    gload_lds16(base + 8192 + d0,        Bt + (long)(n0 + rS) * H_ + tt * 64 + cS);
    gload_lds16(base + 8192 + 4096 + d0, Bt + (long)(n0 + 32 + rS) * H_ + tt * 64 + cS);
    const float* a0 = Wg + (long)(m0 + rS) * 2048 + tt * 64 + cS;
    const float* a1 = Wg + (long)(m0 + 32 + rS) * 2048 + tt * 64 + cS;
    float4 x0 = *(const float4*)a0, x1 = *(const float4*)(a0 + 4);
    float4 y0 = *(const float4*)a1, y1 = *(const float4*)(a1 + 4);
    bf16x8 bx = { (bf16_t)x0.x, (bf16_t)x0.y, (bf16_t)x0.z, (bf16_t)x0.w,
                  (bf16_t)x1.x, (bf16_t)x1.y, (bf16_t)x1.z, (bf16_t)x1.w };
    bf16x8 by = { (bf16_t)y0.x, (bf16_t)y0.y, (bf16_t)y0.z, (bf16_t)y0.w,
                  (bf16_t)y1.x, (bf16_t)y1.y, (bf16_t)y1.z, (bf16_t)y1.w };
    *(bf16x8*)(base + d0) = bx;
    *(bf16x8*)(base + 4096 + d0) = by;
  };

  f32x4 acc[2][2];
  #pragma unroll
  for (int m = 0; m < 2; ++m)
    #pragma unroll
    for (int n = 0; n < 2; ++n) acc[m][n] = (f32x4){0.f, 0.f, 0.f, 0.f};

  stage(0);
  __syncthreads();
  for (int tt = 0; tt < 16; ++tt) {
    if (tt + 1 < 16) stage(tt + 1);
    char* buf = ldsA + (tt & 1) * 16384;
    char* AR = buf + (wm * 32 + fr) * 128;
    char* BR = buf + 8192 + (wn * 32 + fr) * 128;
    bf16x8 a[2][2], b[2][2];
    #pragma unroll
    for (int m = 0; m < 2; ++m) {
      a[m][0] = *(const bf16x8*)(AR + m * 2048 + e0);
      a[m][1] = *(const bf16x8*)(AR + m * 2048 + e1);
      b[m][0] = *(const bf16x8*)(BR + m * 2048 + e0);
      b[m][1] = *(const bf16x8*)(BR + m * 2048 + e1);
    }
    #pragma unroll
    for (int m = 0; m < 2; ++m)
      #pragma unroll
      for (int n = 0; n < 2; ++n) {
        acc[m][n] = __builtin_amdgcn_mfma_f32_16x16x32_bf16(a[m][0], b[n][0], acc[m][n], 0, 0, 0);
        acc[m][n] = __builtin_amdgcn_mfma_f32_16x16x32_bf16(a[m][1], b[n][1], acc[m][n], 0, 0, 0);
      }
    __syncthreads();
  }
  #pragma unroll
  for (int m = 0; m < 2; ++m)
    #pragma unroll
    for (int r_ = 0; r_ < 4; ++r_) {
      int row = m0 + wm * 32 + m * 16 + fq + r_;
      #pragma unroll
      for (int n = 0; n < 2; ++n) {
        int col = n0 + wn * 32 + n * 16 + fr;
        Cw8[(long)(row >> 7) * 131072 + (col >> 5) * 4096 + ((row >> 4) & 7) * 512
            + ((row & 15) + (((col >> 3) & 3) << 4)) * 8 + (col & 7)]
          = to_fp8(acc[m][n][r_] * 16.f);   // x16 into e4m3 normal range
      }
    }
}

// ====== full-row fp8 GEMM + softmax + gate/residual + LayerNorm ============
// R12 core with *** 3-deep wave-private rotation *** (2 stages in flight,
// vmcnt(12) -> ~1040cyc latency cover vs 2-deep's ~520). Fits by moving the
// 20KB param staging POST-loop (params only read in epilogue; staged into
// the then-free wave-buffer region, own-vmcnt(0) before the join barrier).
// LDS: 8 waves x 3 x 6KB = 144KB loop bufs; rvA @147456; red @147712.
// Epilogue params @65536 (post-loop). R15's text-prefetch REVERTED (FETCH
// showed 2x fetch: lines evicted before use).
#define BOFF 16777216   // Wc8p offset from t8p base
__global__ __launch_bounds__(512, 2)
void gemm_ln(const unsigned char* __restrict__ AB,
             const float* __restrict__ textf,
             const float* __restrict__ cbb, const float* __restrict__ agrb,
             const float* __restrict__ gvb, const float* __restrict__ vpb,
             const float* __restrict__ gamma, const float* __restrict__ beta,
             float* __restrict__ out) {
  extern __shared__ __align__(16) char dlds[];
  const int tid  = threadIdx.x;
  const int w    = tid >> 6;
  const int lane = tid & 63;
  const int fr   = lane & 15;
  const int fq   = (lane >> 4) * 4;
  const int bid  = blockIdx.x;
  const long m0  = (long)bid * 64;
  const int bat  = (int)(m0 >> 11);

  // ---- prologue: per-batch softmax over 2048 agr values ----
  {
    float* rvA = (float*)(dlds + 147456);
    float* red = (float*)(dlds + 147712);
    float4 av = *(const float4*)(agrb + (long)bat * 2048 + tid * 4);
    float mloc = fmaxf(fmaxf(av.x, av.y), fmaxf(av.z, av.w)) * 2.f;
    #pragma unroll
    for (int off = 32; off; off >>= 1) mloc = fmaxf(mloc, __shfl_xor(mloc, off));
    if ((tid & 63) == 0) red[tid >> 6] = mloc;
    __syncthreads();
    float mx = red[0];
    #pragma unroll
    for (int i = 1; i < 8; ++i) mx = fmaxf(mx, red[i]);
    float sl = __expf(2.f * av.x - mx) + __expf(2.f * av.y - mx)
             + __expf(2.f * av.z - mx) + __expf(2.f * av.w - mx);
    #pragma unroll
    for (int off = 32; off; off >>= 1) sl += __shfl_xor(sl, off);
    __syncthreads();
    if ((tid & 63) == 0) red[tid >> 6] = sl;
    __syncthreads();
    float ssum = red[0] + red[1] + red[2] + red[3]
               + red[4] + red[5] + red[6] + red[7];
    if (tid < 64) rvA[tid] = __expf(2.f * agrb[m0 + tid] - mx) / ssum;
    __syncthreads();
  }

  // wave-private staging pointers (kb-major packed layouts)
  const unsigned char* aSrc = AB + (long)bid * 65536 + lane * 16;
  const unsigned char* bSrc = AB + BOFF + (long)w * 131072 + lane * 16;
  char* const wBase = dlds + w * 18432;          // 3 x 6144 per wave

  f32x4 acc[4][8];
  #pragma unroll
  for (int m = 0; m < 4; ++m)
    #pragma unroll
    for (int n = 0; n < 8; ++n) acc[m][n] = (f32x4){0.f, 0.f, 0.f, 0.f};

#define STAGE(t)                                                        \
  {                                                                     \
    char* D_ = wBase + ((t) % 3) * 6144 + lane * 16;                    \
    const unsigned char* As_ = aSrc + (t) * 2048;                       \
    gload_lds16(D_,        As_);                                        \
    gload_lds16(D_ + 1024, As_ + 1024);                                 \
    const unsigned char* Bs_ = bSrc + (t) * 4096;                       \
    _Pragma("unroll")                                                   \
    for (int r_ = 0; r_ < 4; ++r_)                                      \
      gload_lds16(D_ + 2048 + r_ * 1024, Bs_ + r_ * 1024);              \
  }
#define KITER(t, WN)                                                    \
  {                                                                     \
    asm volatile("s_waitcnt lgkmcnt(0)" ::: "memory");                  \
    __builtin_amdgcn_sched_barrier(0);                                  \
    if ((t) + 2 < 32) STAGE((t) + 2)                                    \
    asm volatile("s_waitcnt vmcnt(" #WN ")" ::: "memory");              \
    __builtin_amdgcn_sched_barrier(0);                                  \
    const char* R_ = wBase + ((t) % 3) * 6144 + lane * 8;               \
    long a_[4], b_[8];                                                  \
    _Pragma("unroll")                                                   \
    for (int m_ = 0; m_ < 4; ++m_)                                      \
      a_[m_] = *(const long*)(R_ + m_ * 512);                           \
    _Pragma("unroll")                                                   \
    for (int n_ = 0; n_ < 8; ++n_)                                      \
      b_[n_] = *(const long*)(R_ + 2048 + n_ * 512);                    \
    _Pragma("unroll")                                                   \
    for (int m_ = 0; m_ < 4; ++m_)                                      \
      _Pragma("unroll")                                                 \
      for (int n_ = 0; n_ < 8; ++n_)                                    \
        acc[m_][n_] = __builtin_amdgcn_mfma_f32_16x16x32_fp8_fp8(       \
            a_[m_], b_[n_], acc[m_][n_], 0, 0, 0);                      \
  }

  STAGE(0)
  asm volatile("" ::: "memory");
  STAGE(1)

  KITER(0, 12)  KITER(1, 12)  KITER(2, 12)  KITER(3, 12)
  KITER(4, 12)  KITER(5, 12)  KITER(6, 12)  KITER(7, 12)
  KITER(8, 12)  KITER(9, 12)  KITER(10, 12) KITER(11, 12)
  KITER(12, 12) KITER(13, 12) KITER(14, 12) KITER(15, 12)
  KITER(16, 12) KITER(17, 12) KITER(18, 12) KITER(19, 12)
  KITER(20, 12) KITER(21, 12) KITER(22, 12) KITER(23, 12)
  KITER(24, 12) KITER(25, 12) KITER(26, 12) KITER(27, 12)
  KITER(28, 12) KITER(29, 12)
  KITER(30, 6)
  KITER(31, 0)
#undef KITER
#undef STAGE

  // ---- post-loop: stage per-column params into now-free LDS @65536 -------
  __syncthreads();                      // all waves done with loop bufs
  char* P = dlds + 65536;
  {
    if (tid < 256) {
      gload_lds16(P + tid * 16,          cbb + tid * 4);
      gload_lds16(P + 8192 + tid * 16,   vpb + bat * H_ + tid * 4);
      gload_lds16(P + 16384 + tid * 16,  beta + tid * 4);
    } else {
      int t2 = tid - 256;
      gload_lds16(P + 4096 + t2 * 16,    gvb + bat * H_ + t2 * 4);
      gload_lds16(P + 12288 + t2 * 16,   gamma + t2 * 4);
    }
    asm volatile("s_waitcnt vmcnt(0)" ::: "memory");  // own loads landed
  }

  // ---- epilogue: 4 passes of 16 rows; LDS transpose -> coalesced ----------
  const int lr = tid >> 5;              // local row 0..15
  const int jj = tid & 31;              // col-chunk owner
  const float* rvA = (const float*)(dlds + 147456);

  #pragma unroll
  for (int m = 0; m < 4; ++m) {
    __syncthreads();                    // joins param-DMA too (pass 0)
    #pragma unroll
    for (int n = 0; n < 8; ++n) {
      #pragma unroll
      for (int r = 0; r < 4; ++r) {
        int rl = fq + r;
        int c  = (w * 128 + n * 16 + fr) ^ (((rl >> 2) & 3) << 4);
        *(float*)(dlds + rl * 4096 + c * 4) = acc[m][n][r];
      }
    }
    __syncthreads();
    long row = m0 + m * 16 + lr;
    float rv = rvA[m * 16 + lr];
    const float* tf = textf + row * H_;
    const int rot = ((lr >> 2) & 3) << 4;
    float s = 0.f, q = 0.f;
    #pragma unroll 2
    for (int k = 0; k < 8; ++k) {
      int c0 = k * 128 + jj * 4;        // coalesced: 32 lanes cover 128 cols
      char* slot = dlds + lr * 4096 + ((c0 ^ rot) * 4);
      f32x4 a4 = *(const f32x4*)slot;
      float4 t4  = *(const float4*)(tf + c0);
      f32x4 cb4 = *(const f32x4*)(P + c0 * 4);
      f32x4 gv4 = *(const f32x4*)(P + 4096 + c0 * 4);
      f32x4 vp4 = *(const f32x4*)(P + 8192 + c0 * 4);
      f32x4 f4;
      float gp, g;
      gp = a4[0] * 0.0625f + cb4[0] + rv * gv4[0];
      g = 1.f / (1.f + __expf(-gp));
      f4[0] = t4.x + g * rv * vp4[0];
      gp = a4[1] * 0.0625f + cb4[1] + rv * gv4[1];
      g = 1.f / (1.f + __expf(-gp));
      f4[1] = t4.y + g * rv * vp4[1];
      gp = a4[2] * 0.0625f + cb4[2] + rv * gv4[2];
      g = 1.f / (1.f + __expf(-gp));
      f4[2] = t4.z + g * rv * vp4[2];
      gp = a4[3] * 0.0625f + cb4[3] + rv * gv4[3];
      g = 1.f / (1.f + __expf(-gp));
      f4[3] = t4.w + g * rv * vp4[3];
      *(f32x4*)slot = f4;               // fused value back to same slot
      s += f4[0] + f4[1] + f4[2] + f4[3];
      q += f4[0] * f4[0] + f4[1] * f4[1] + f4[2] * f4[2] + f4[3] * f4[3];
    }
    #pragma unroll
    for (int off = 1; off < 32; off <<= 1) {   // row stats over its 32 lanes
      s += __shfl_xor(s, off);
      q += __shfl_xor(q, off);
    }
    float mu  = s * (1.f / H_);
    float var = q * (1.f / H_) - mu * mu;
    float inv = rsqrtf(var + 1e-5f);
    float* op = out + row * H_;
    #pragma unroll 2
    for (int k = 0; k < 8; ++k) {
      int c0 = k * 128 + jj * 4;
      f32x4 f4 = *(const f32x4*)(dlds + lr * 4096 + ((c0 ^ rot) * 4));
      f32x4 gg = *(const f32x4*)(P + 12288 + c0 * 4);
      f32x4 bb = *(const f32x4*)(P + 16384 + c0 * 4);
      float4 o4;
      o4.x = (f4[0] - mu) * inv * gg[0] + bb[0];
      o4.y = (f4[1] - mu) * inv * gg[1] + bb[1];
      o4.z = (f4[2] - mu) * inv * gg[2] + bb[2];
      o4.w = (f4[3] - mu) * inv * gg[3] + bb[3];
      *(float4*)(op + c0) = o4;
    }
  }
}

extern "C" void kernel_launch(void* const* d_in, const int* in_sizes, int n_in,
                              void* d_out, int out_size, void* d_ws, size_t ws_size,
                              hipStream_t stream) {
  const float* text  = (const float*)d_in[0];
  const float* vis   = (const float*)d_in[1];
  const float* Wt    = (const float*)d_in[2];
  const float* bt    = (const float*)d_in[3];
  const float* Wv    = (const float*)d_in[4];
  const float* bv    = (const float*)d_in[5];
  const float* Wg    = (const float*)d_in[6];
  const float* bg    = (const float*)d_in[7];
  const float* gamma = (const float*)d_in[8];
  const float* beta  = (const float*)d_in[9];
  float* out = (float*)d_out;

  char* ws = (char*)d_ws;
  unsigned char* t8p   = (unsigned char*)(ws);                    // 16 MiB (packed A)
  unsigned char* Wc8p  = (unsigned char*)(ws + (size_t)16777216); // 1 MiB (packed B)
  bf16_t* WtT_b = (bf16_t*)(ws + (size_t)17825792);               // 2 MiB
  float*  pooled = (float*)(ws + (size_t)19922944);               // 32 KiB
  float*  vp     = (float*)(ws + (size_t)19955712);               // 32 KiB
  float*  gv     = (float*)(ws + (size_t)19988480);               // 32 KiB
  float*  u      = (float*)(ws + (size_t)20021248);               // 32 KiB
  float*  cbb    = (float*)(ws + (size_t)20054016);               // 4 KiB
  float*  agr    = (float*)(ws + (size_t)20123648);               // 64 KiB

  static bool smem_set = false;
  if (!smem_set) {
    (void)hipFuncSetAttribute((const void*)gemm_ln,
                              hipFuncAttributeMaxDynamicSharedMemorySize, 147776);
    smem_set = true;
  }

  prep1<<<584, 256, 0, stream>>>(vis, Wt, Wg, bt, bg, pooled, WtT_b, cbb, u);
  matvec8<<<256, 256, 0, stream>>>(Wv, 1024, 0, pooled, bv, vp);  // vp
  prep3<<<512, 256, 0, stream>>>(Wg, Wt, vp, gv, u);              // gv + u
  cvt_wc<<<1280, 256, 0, stream>>>(text, u, Wg, WtT_b, t8p, agr, Wc8p);
  gemm_ln<<<256, 512, 147776, stream>>>(t8p, text, cbb, agr, gv, vp,
                                        gamma, beta, out);
}

// Round 17
// 97.191 us; speedup vs baseline: 1.0471x; 1.0240x over previous
//
#include <hip/hip_runtime.h>
#include <hip/hip_bf16.h>
#include <hip/hip_fp8.h>

typedef __bf16 bf16_t;
typedef bf16_t bf16x4 __attribute__((ext_vector_type(4)));
typedef bf16_t bf16x8 __attribute__((ext_vector_type(8)));
typedef float  f32x4  __attribute__((ext_vector_type(4)));

#define B_  8
#define L_  2048
#define H_  1024
#define LV_ 256

typedef const __attribute__((address_space(1))) void* gptr_as1;
typedef __attribute__((address_space(3))) void* lptr_as3;

__device__ __forceinline__ void gload_lds16(void* lds_base, const void* gsrc) {
  __builtin_amdgcn_global_load_lds((gptr_as1)gsrc, (lptr_as3)lds_base, 16, 0, 0);
}

__device__ __forceinline__ unsigned char to_fp8(float x) {
  return __hip_fp8_e4m3(x).__x;
}
__device__ __forceinline__ float from_fp8(unsigned char b) {
  __hip_fp8_e4m3 v; v.__x = b; return (float)v;
}

// ==== K1: vpool(64) | WtT(256) | cbb(256) | zero-u(8) | text-pack(1024) ====
// text-pack has NO dependencies -> its ~13us of HBM traffic overlaps the
// small ops in one launch (was serialized at the end of the chain).
__global__ __launch_bounds__(256) void prep1(const float* __restrict__ vf,
                                             const float* __restrict__ Wt,
                                             const float* __restrict__ Wg,
                                             const float* __restrict__ bt,
                                             const float* __restrict__ bg,
                                             const float* __restrict__ text,
                                             float* __restrict__ pooled,
                                             bf16_t* __restrict__ WtT,
                                             float* __restrict__ cbb,
                                             float* __restrict__ u,
                                             unsigned char* __restrict__ t8p) {
  __shared__ __align__(16) char shm[16640];
  int bid = blockIdx.x;
  int t = threadIdx.x;
  if (bid < 64) {                       // vision mean-pool
    float* part = (float*)shm;
    int b = bid >> 3, hc = bid & 7;
    int h = hc * 128 + (t & 127);
    int kh = t >> 7;
    const float* p = vf + (long)b * (LV_ * H_) + (long)kh * 128 * H_ + h;
    float s = 0.f;
    #pragma unroll 4
    for (int k = 0; k < 128; ++k) s += p[k * H_];
    part[t] = s;
    __syncthreads();
    if (t < 128)
      pooled[b * H_ + hc * 128 + t] = (part[t] + part[t + 128]) * (1.f / 256.f);
  } else if (bid < 320) {               // Wt transpose-convert -> bf16
    float (*tile)[65] = (float(*)[65])shm;
    int lb = bid - 64;
    int hr = (lb >> 4) * 64;
    int ec = (lb & 15) * 64;
    int lr = t >> 4, lc = t & 15;
    #pragma unroll
    for (int rr = 0; rr < 4; ++rr) {
      int r = rr * 16 + lr;
      float4 v = *(const float4*)(Wt + (long)(hr + r) * H_ + ec + lc * 4);
      tile[r][lc * 4 + 0] = v.x; tile[r][lc * 4 + 1] = v.y;
      tile[r][lc * 4 + 2] = v.z; tile[r][lc * 4 + 3] = v.w;
    }
    __syncthreads();
    #pragma unroll
    for (int rr = 0; rr < 4; ++rr) {
      int er = rr * 16 + lr;
      bf16x4 o = { (bf16_t)tile[lc * 4 + 0][er], (bf16_t)tile[lc * 4 + 1][er],
                   (bf16_t)tile[lc * 4 + 2][er], (bf16_t)tile[lc * 4 + 3][er] };
      *(bf16x4*)(WtT + (long)(ec + er) * H_ + hr + lc * 4) = o;
    }
  } else if (bid < 576) {               // cbb = Wg[:, :H] @ bt + bg
    int lb = bid - 320;
    int wid = t >> 6, lane = t & 63;
    int o = lb * 4 + wid;
    const float* wr = Wg + (long)o * 2048;
    float acc = 0.f;
    for (int j = 0; j < 16; ++j) acc += wr[lane + 64 * j] * bt[lane + 64 * j];
    for (int off = 32; off; off >>= 1) acc += __shfl_down(acc, off);
    if (lane == 0) cbb[o] = acc + bg[o];
  } else if (bid < 584) {               // zero u (for K3 atomics)
    int z = bid - 576;
    *(float4*)(u + z * 1024 + t * 4) = (float4){0.f, 0.f, 0.f, 0.f};
  } else {                              // text -> fp8 frag-pack (kb-major)
    int pb = bid - 584;                 // 0..1023
    unsigned char (*q8)[1032] = (unsigned char(*)[1032])shm;  // +8B row pad
    int wid = t >> 6, lane = t & 63;
    const float4* trow = (const float4*)(text + (long)pb * (16 * H_));
    #pragma unroll 4
    for (int i = 0; i < 16; ++i) {      // i = row within 16-row block
      float4 v = trow[i * 256 + t];     // coalesced
      uchar4 qq = { to_fp8(v.x), to_fp8(v.y), to_fp8(v.z), to_fp8(v.w) };
      *(uchar4*)&q8[i][t * 4] = qq;
    }
    __syncthreads();
    unsigned char* dst = t8p + (long)(pb >> 2) * 65536 + (pb & 3) * 512;
    #pragma unroll
    for (int c = 0; c < 8; ++c) {
      int kb = wid * 8 + c;
      uint2 r = *(const uint2*)&q8[lane & 15][kb * 32 + (lane >> 4) * 8];
      *(uint2*)(dst + kb * 2048 + lane * 8) = r;    // coalesced 512B/wave
    }
  }
}

// ------- out[b][o] = sum_h x[b][h]*W[o*ldw+woff+h] (+bias), 8 batches ------
__global__ void matvec8(const float* __restrict__ W, int ldw, int woff,
                        const float* __restrict__ x,
                        const float* __restrict__ bias,
                        float* __restrict__ out) {
  int wid = threadIdx.x >> 6, lane = threadIdx.x & 63;
  int o = blockIdx.x * 4 + wid;
  const float* wr = W + (long)o * ldw + woff;
  float acc[B_];
  #pragma unroll
  for (int b = 0; b < B_; ++b) acc[b] = 0.f;
  for (int j = 0; j < 16; ++j) {
    float w = wr[lane + 64 * j];
    #pragma unroll
    for (int b = 0; b < B_; ++b) acc[b] += w * x[b * H_ + lane + 64 * j];
  }
  #pragma unroll
  for (int b = 0; b < B_; ++b)
    for (int off = 32; off; off >>= 1) acc[b] += __shfl_down(acc[b], off);
  if (lane == 0) {
    float bb = bias ? bias[o] : 0.f;
    #pragma unroll
    for (int b = 0; b < B_; ++b) out[b * H_ + o] = acc[b] + bb;
  }
}

// ==== K3: gv(256) | u += Wt^T vp partials via atomics(256) =================
__global__ __launch_bounds__(256) void prep3(const float* __restrict__ Wg,
                                             const float* __restrict__ Wt,
                                             const float* __restrict__ vp,
                                             float* __restrict__ gv,
                                             float* __restrict__ u) {
  int bid = blockIdx.x;
  int t = threadIdx.x;
  if (bid < 256) {                      // gv = Wg[:, H:] @ vp
    int wid = t >> 6, lane = t & 63;
    int o = bid * 4 + wid;
    const float* wr = Wg + (long)o * 2048 + 1024;
    float acc[B_];
    #pragma unroll
    for (int b = 0; b < B_; ++b) acc[b] = 0.f;
    for (int j = 0; j < 16; ++j) {
      float w = wr[lane + 64 * j];
      #pragma unroll
      for (int b = 0; b < B_; ++b) acc[b] += w * vp[b * H_ + lane + 64 * j];
    }
    #pragma unroll
    for (int b = 0; b < B_; ++b)
      for (int off = 32; off; off >>= 1) acc[b] += __shfl_down(acc[b], off);
    if (lane == 0) {
      #pragma unroll
      for (int b = 0; b < B_; ++b) gv[b * H_ + o] = acc[b];
    }
  } else {                              // u[b][e] += sum_{o in chunk} Wt[o][e]*vp[b][o]
    int lb = bid - 256;                 // eb(4) x oc(64)
    int e = (lb & 3) * 256 + t;
    int oc = lb >> 2;
    float a[B_];
    #pragma unroll
    for (int b = 0; b < B_; ++b) a[b] = 0.f;
    #pragma unroll
    for (int i = 0; i < 16; ++i) {
      int o = oc * 16 + i;
      float w = Wt[(long)o * H_ + e];
      #pragma unroll
      for (int b = 0; b < B_; ++b) a[b] += w * vp[b * H_ + o];
    }
    #pragma unroll
    for (int b = 0; b < B_; ++b) atomicAdd(u + b * 1024 + e, a[b]);
  }
}

// ==== K4: [0,256) agr from PACKED fp8 text (16MB read, not 64MB);
//          [256,512) Wc8p = frag-packed fp8(16 * Wg[:, :H] @ WtT) ==========
__global__ __launch_bounds__(256) void agwc(const unsigned char* __restrict__ t8p,
                                            const float* __restrict__ u,
                                            const float* __restrict__ Wg,
                                            const bf16_t* __restrict__ Bt,
                                            float* __restrict__ agr,
                                            unsigned char* __restrict__ Cw8) {
  __shared__ __align__(16) char shm[32800];
  int bid = blockIdx.x;
  int t = threadIdx.x;
  if (bid < 256) {
    // block handles mb-quad q=bid: 64 rows, bytes [q*65536, +65536)
    float* uL = (float*)shm;            // u[b] staged: 4KB
    int b = bid >> 5;
    ((float4*)uL)[t] = ((const float4*)(u + b * 1024))[t];
    __syncthreads();
    int mb_l = t >> 6, li = t & 63;
    int row = li & 15, p = li >> 4;
    const unsigned char* src = t8p + (long)bid * 65536 + mb_l * 512 + li * 8;
    float s = 0.f;
    #pragma unroll 4
    for (int kb = 0; kb < 32; ++kb) {
      uint2 d = *(const uint2*)(src + kb * 2048);
      const float* up = uL + kb * 32 + p * 8;
      #pragma unroll
      for (int j = 0; j < 4; ++j)
        s += from_fp8((unsigned char)(d.x >> (8 * j))) * up[j];
      #pragma unroll
      for (int j = 0; j < 4; ++j)
        s += from_fp8((unsigned char)(d.y >> (8 * j))) * up[4 + j];
    }
    s += __shfl_xor(s, 16);
    s += __shfl_xor(s, 32);             // sum over the 4 k-strips of the row
    if (p == 0) agr[(long)bid * 64 + mb_l * 16 + row] = s;
    return;
  }
  // ---- Wc8p GEMM (kb-major packed output) ----
  const int tid = t;
  const int wid = tid >> 6, lane = tid & 63;
  const int fr = lane & 15, fkb = (lane >> 4) * 16, fq = (lane >> 4) * 4;
  const int wm = wid >> 1, wn = wid & 1;
  const int lb = bid - 256;
  const int tm = lb & 15, tn = lb >> 4;
  const int m0 = tm * 64, n0 = tn * 64;

  char* ldsA = shm;                     // [2][16384]

  const int d0 = tid * 16;
  const int p  = d0 ^ (((d0 >> 7) & 7) << 4);
  const int rS = p >> 7, cS = (p & 127) >> 1;

  const int swz = (fr & 7) << 4;
  const int e0 = fkb ^ swz;
  const int e1 = (64 + fkb) ^ swz;

  auto stage = [&](int tt) {
    char* base = ldsA + (tt & 1) * 16384;
    gload_lds16(base + 8192 + d0,        Bt + (long)(n0 + rS) * H_ + tt * 64 + cS);
    gload_lds16(base + 8192 + 4096 + d0, Bt + (long)(n0 + 32 + rS) * H_ + tt * 64 + cS);
    const float* a0 = Wg + (long)(m0 + rS) * 2048 + tt * 64 + cS;
    const float* a1 = Wg + (long)(m0 + 32 + rS) * 2048 + tt * 64 + cS;
    float4 x0 = *(const float4*)a0, x1 = *(const float4*)(a0 + 4);
    float4 y0 = *(const float4*)a1, y1 = *(const float4*)(a1 + 4);
    bf16x8 bx = { (bf16_t)x0.x, (bf16_t)x0.y, (bf16_t)x0.z, (bf16_t)x0.w,
                  (bf16_t)x1.x, (bf16_t)x1.y, (bf16_t)x1.z, (bf16_t)x1.w };
    bf16x8 by = { (bf16_t)y0.x, (bf16_t)y0.y, (bf16_t)y0.z, (bf16_t)y0.w,
                  (bf16_t)y1.x, (bf16_t)y1.y, (bf16_t)y1.z, (bf16_t)y1.w };
    *(bf16x8*)(base + d0) = bx;
    *(bf16x8*)(base + 4096 + d0) = by;
  };

  f32x4 acc[2][2];
  #pragma unroll
  for (int m = 0; m < 2; ++m)
    #pragma unroll
    for (int n = 0; n < 2; ++n) acc[m][n] = (f32x4){0.f, 0.f, 0.f, 0.f};

  stage(0);
  __syncthreads();
  for (int tt = 0; tt < 16; ++tt) {
    if (tt + 1 < 16) stage(tt + 1);
    char* buf = ldsA + (tt & 1) * 16384;
    char* AR = buf + (wm * 32 + fr) * 128;
    char* BR = buf + 8192 + (wn * 32 + fr) * 128;
    bf16x8 a[2][2], b[2][2];
    #pragma unroll
    for (int m = 0; m < 2; ++m) {
      a[m][0] = *(const bf16x8*)(AR + m * 2048 + e0);
      a[m][1] = *(const bf16x8*)(AR + m * 2048 + e1);
      b[m][0] = *(const bf16x8*)(BR + m * 2048 + e0);
      b[m][1] = *(const bf16x8*)(BR + m * 2048 + e1);
    }
    #pragma unroll
    for (int m = 0; m < 2; ++m)
      #pragma unroll
      for (int n = 0; n < 2; ++n) {
        acc[m][n] = __builtin_amdgcn_mfma_f32_16x16x32_bf16(a[m][0], b[n][0], acc[m][n], 0, 0, 0);
        acc[m][n] = __builtin_amdgcn_mfma_f32_16x16x32_bf16(a[m][1], b[n][1], acc[m][n], 0, 0, 0);
      }
    __syncthreads();
  }
  #pragma unroll
  for (int m = 0; m < 2; ++m)
    #pragma unroll
    for (int r_ = 0; r_ < 4; ++r_) {
      int row = m0 + wm * 32 + m * 16 + fq + r_;
      #pragma unroll
      for (int n = 0; n < 2; ++n) {
        int col = n0 + wn * 32 + n * 16 + fr;
        Cw8[(long)(row >> 7) * 131072 + (col >> 5) * 4096 + ((row >> 4) & 7) * 512
            + ((row & 15) + (((col >> 3) & 3) << 4)) * 8 + (col & 7)]
          = to_fp8(acc[m][n][r_] * 16.f);   // x16 into e4m3 normal range
      }
    }
}

// ====== full-row fp8 GEMM + softmax + gate/residual + LayerNorm ============
// R12 core, verified 49.5us: barrier-free wave-private staging (2-deep,
// vmcnt(6)), kb-major packed A/B, coalesced LDS-transpose epilogue,
// params in LDS. Loop is L2-BW-bound (48KB/tile/CU) -- structural plateau.
#define BOFF 16777216   // Wc8p offset from t8p base
__global__ __launch_bounds__(512, 2)
void gemm_ln(const unsigned char* __restrict__ AB,
             const float* __restrict__ textf,
             const float* __restrict__ cbb, const float* __restrict__ agrb,
             const float* __restrict__ gvb, const float* __restrict__ vpb,
             const float* __restrict__ gamma, const float* __restrict__ beta,
             float* __restrict__ out) {
  extern __shared__ __align__(16) char dlds[];
  // wave w loop bufs: [w*12288, +12288) = 2 x {A 2K, B 4K}
  // params @98304 (20KB); red @118784; rvA @118848; epi transpose tile @0
  const int tid  = threadIdx.x;
  const int w    = tid >> 6;
  const int lane = tid & 63;
  const int fr   = lane & 15;
  const int fq   = (lane >> 4) * 4;
  const int bid  = blockIdx.x;
  const long m0  = (long)bid * 64;
  const int bat  = (int)(m0 >> 11);

  // ---- prologue: per-batch softmax over 2048 agr values ----
  {
    float* red = (float*)(dlds + 118784);
    float* rvA = (float*)(dlds + 118848);
    float4 av = *(const float4*)(agrb + (long)bat * 2048 + tid * 4);
    float mloc = fmaxf(fmaxf(av.x, av.y), fmaxf(av.z, av.w)) * 2.f;
    #pragma unroll
    for (int off = 32; off; off >>= 1) mloc = fmaxf(mloc, __shfl_xor(mloc, off));
    if ((tid & 63) == 0) red[tid >> 6] = mloc;
    __syncthreads();
    float mx = red[0];
    #pragma unroll
    for (int i = 1; i < 8; ++i) mx = fmaxf(mx, red[i]);
    float sl = __expf(2.f * av.x - mx) + __expf(2.f * av.y - mx)
             + __expf(2.f * av.z - mx) + __expf(2.f * av.w - mx);
    #pragma unroll
    for (int off = 32; off; off >>= 1) sl += __shfl_xor(sl, off);
    __syncthreads();
    if ((tid & 63) == 0) red[tid >> 6] = sl;
    __syncthreads();
    float ssum = red[0] + red[1] + red[2] + red[3]
               + red[4] + red[5] + red[6] + red[7];
    if (tid < 64) rvA[tid] = __expf(2.f * agrb[m0 + tid] - mx) / ssum;
    __syncthreads();
  }

  // ---- stage per-column params into LDS (once; drained by tile-0 vmcnt) --
  {
    char* P = dlds + 98304;
    if (tid < 256) {
      gload_lds16(P + tid * 16,          cbb + tid * 4);
      gload_lds16(P + 8192 + tid * 16,   vpb + bat * H_ + tid * 4);
      gload_lds16(P + 16384 + tid * 16,  beta + tid * 4);
    } else {
      int t2 = tid - 256;
      gload_lds16(P + 4096 + t2 * 16,    gvb + bat * H_ + t2 * 4);
      gload_lds16(P + 12288 + t2 * 16,   gamma + t2 * 4);
    }
  }

  // wave-private staging pointers (kb-major packed layouts)
  const unsigned char* aSrc = AB + (long)bid * 65536 + lane * 16;
  const unsigned char* bSrc = AB + BOFF + (long)w * 131072 + lane * 16;
  char* const wBase = dlds + w * 12288;

  f32x4 acc[4][8];
  #pragma unroll
  for (int m = 0; m < 4; ++m)
    #pragma unroll
    for (int n = 0; n < 8; ++n) acc[m][n] = (f32x4){0.f, 0.f, 0.f, 0.f};

#define STAGE(t)                                                        \
  {                                                                     \
    char* D_ = wBase + ((t) & 1) * 6144 + lane * 16;                    \
    const unsigned char* As_ = aSrc + (t) * 2048;                       \
    gload_lds16(D_,        As_);                                        \
    gload_lds16(D_ + 1024, As_ + 1024);                                 \
    const unsigned char* Bs_ = bSrc + (t) * 4096;                       \
    _Pragma("unroll")                                                   \
    for (int r_ = 0; r_ < 4; ++r_)                                      \
      gload_lds16(D_ + 2048 + r_ * 1024, Bs_ + r_ * 1024);              \
  }
#define KITER(t, WN)                                                    \
  {                                                                     \
    asm volatile("s_waitcnt lgkmcnt(0)" ::: "memory");                  \
    __builtin_amdgcn_sched_barrier(0);                                  \
    if ((t) + 1 < 32) STAGE((t) + 1)                                    \
    asm volatile("s_waitcnt vmcnt(" #WN ")" ::: "memory");              \
    __builtin_amdgcn_sched_barrier(0);                                  \
    const char* R_ = wBase + ((t) & 1) * 6144 + lane * 8;               \
    long a_[4], b_[8];                                                  \
    _Pragma("unroll")                                                   \
    for (int m_ = 0; m_ < 4; ++m_)                                      \
      a_[m_] = *(const long*)(R_ + m_ * 512);                           \
    _Pragma("unroll")                                                   \
    for (int n_ = 0; n_ < 8; ++n_)                                      \
      b_[n_] = *(const long*)(R_ + 2048 + n_ * 512);                    \
    _Pragma("unroll")                                                   \
    for (int m_ = 0; m_ < 4; ++m_)                                      \
      _Pragma("unroll")                                                 \
      for (int n_ = 0; n_ < 8; ++n_)                                    \
        acc[m_][n_] = __builtin_amdgcn_mfma_f32_16x16x32_fp8_fp8(       \
            a_[m_], b_[n_], acc[m_][n_], 0, 0, 0);                      \
  }

  STAGE(0)

  KITER(0, 6)  KITER(1, 6)  KITER(2, 6)  KITER(3, 6)
  KITER(4, 6)  KITER(5, 6)  KITER(6, 6)  KITER(7, 6)
  KITER(8, 6)  KITER(9, 6)  KITER(10, 6) KITER(11, 6)
  KITER(12, 6) KITER(13, 6) KITER(14, 6) KITER(15, 6)
  KITER(16, 6) KITER(17, 6) KITER(18, 6) KITER(19, 6)
  KITER(20, 6) KITER(21, 6) KITER(22, 6) KITER(23, 6)
  KITER(24, 6) KITER(25, 6) KITER(26, 6) KITER(27, 6)
  KITER(28, 6) KITER(29, 6) KITER(30, 6) KITER(31, 0)
#undef KITER
#undef STAGE

  // ---- epilogue: 4 passes of 16 rows; LDS transpose -> coalesced ----------
  const int lr = tid >> 5;              // local row 0..15
  const int jj = tid & 31;              // col-chunk owner
  char* P = dlds + 98304;
  const float* rvA = (const float*)(dlds + 118848);

  #pragma unroll
  for (int m = 0; m < 4; ++m) {
    __syncthreads();                    // converge; LDS loop bufs now free
    #pragma unroll
    for (int n = 0; n < 8; ++n) {
      #pragma unroll
      for (int r = 0; r < 4; ++r) {
        int rl = fq + r;
        int c  = (w * 128 + n * 16 + fr) ^ (((rl >> 2) & 3) << 4);
        *(float*)(dlds + rl * 4096 + c * 4) = acc[m][n][r];
      }
    }
    __syncthreads();
    long row = m0 + m * 16 + lr;
    float rv = rvA[m * 16 + lr];
    const float* tf = textf + row * H_;
    const int rot = ((lr >> 2) & 3) << 4;
    float s = 0.f, q = 0.f;
    #pragma unroll 2
    for (int k = 0; k < 8; ++k) {
      int c0 = k * 128 + jj * 4;        // coalesced: 32 lanes cover 128 cols
      char* slot = dlds + lr * 4096 + ((c0 ^ rot) * 4);
      f32x4 a4 = *(const f32x4*)slot;
      float4 t4  = *(const float4*)(tf + c0);
      f32x4 cb4 = *(const f32x4*)(P + c0 * 4);
      f32x4 gv4 = *(const f32x4*)(P + 4096 + c0 * 4);
      f32x4 vp4 = *(const f32x4*)(P + 8192 + c0 * 4);
      f32x4 f4;
      float gp, g;
      gp = a4[0] * 0.0625f + cb4[0] + rv * gv4[0];
      g = 1.f / (1.f + __expf(-gp));
      f4[0] = t4.x + g * rv * vp4[0];
      gp = a4[1] * 0.0625f + cb4[1] + rv * gv4[1];
      g = 1.f / (1.f + __expf(-gp));
      f4[1] = t4.y + g * rv * vp4[1];
      gp = a4[2] * 0.0625f + cb4[2] + rv * gv4[2];
      g = 1.f / (1.f + __expf(-gp));
      f4[2] = t4.z + g * rv * vp4[2];
      gp = a4[3] * 0.0625f + cb4[3] + rv * gv4[3];
      g = 1.f / (1.f + __expf(-gp));
      f4[3] = t4.w + g * rv * vp4[3];
      *(f32x4*)slot = f4;               // fused value back to same slot
      s += f4[0] + f4[1] + f4[2] + f4[3];
      q += f4[0] * f4[0] + f4[1] * f4[1] + f4[2] * f4[2] + f4[3] * f4[3];
    }
    #pragma unroll
    for (int off = 1; off < 32; off <<= 1) {   // row stats over its 32 lanes
      s += __shfl_xor(s, off);
      q += __shfl_xor(q, off);
    }
    float mu  = s * (1.f / H_);
    float var = q * (1.f / H_) - mu * mu;
    float inv = rsqrtf(var + 1e-5f);
    float* op = out + row * H_;
    #pragma unroll 2
    for (int k = 0; k < 8; ++k) {
      int c0 = k * 128 + jj * 4;
      f32x4 f4 = *(const f32x4*)(dlds + lr * 4096 + ((c0 ^ rot) * 4));
      f32x4 gg = *(const f32x4*)(P + 12288 + c0 * 4);
      f32x4 bb = *(const f32x4*)(P + 16384 + c0 * 4);
      float4 o4;
      o4.x = (f4[0] - mu) * inv * gg[0] + bb[0];
      o4.y = (f4[1] - mu) * inv * gg[1] + bb[1];
      o4.z = (f4[2] - mu) * inv * gg[2] + bb[2];
      o4.w = (f4[3] - mu) * inv * gg[3] + bb[3];
      *(float4*)(op + c0) = o4;
    }
  }
}

extern "C" void kernel_launch(void* const* d_in, const int* in_sizes, int n_in,
                              void* d_out, int out_size, void* d_ws, size_t ws_size,
                              hipStream_t stream) {
  const float* text  = (const float*)d_in[0];
  const float* vis   = (const float*)d_in[1];
  const float* Wt    = (const float*)d_in[2];
  const float* bt    = (const float*)d_in[3];
  const float* Wv    = (const float*)d_in[4];
  const float* bv    = (const float*)d_in[5];
  const float* Wg    = (const float*)d_in[6];
  const float* bg    = (const float*)d_in[7];
  const float* gamma = (const float*)d_in[8];
  const float* beta  = (const float*)d_in[9];
  float* out = (float*)d_out;

  char* ws = (char*)d_ws;
  unsigned char* t8p   = (unsigned char*)(ws);                    // 16 MiB (packed A)
  unsigned char* Wc8p  = (unsigned char*)(ws + (size_t)16777216); // 1 MiB (packed B)
  bf16_t* WtT_b = (bf16_t*)(ws + (size_t)17825792);               // 2 MiB
  float*  pooled = (float*)(ws + (size_t)19922944);               // 32 KiB
  float*  vp     = (float*)(ws + (size_t)19955712);               // 32 KiB
  float*  gv     = (float*)(ws + (size_t)19988480);               // 32 KiB
  float*  u      = (float*)(ws + (size_t)20021248);               // 32 KiB
  float*  cbb    = (float*)(ws + (size_t)20054016);               // 4 KiB
  float*  agr    = (float*)(ws + (size_t)20123648);               // 64 KiB

  static bool smem_set = false;
  if (!smem_set) {
    (void)hipFuncSetAttribute((const void*)gemm_ln,
                              hipFuncAttributeMaxDynamicSharedMemorySize, 119296);
    smem_set = true;
  }

  prep1<<<1608, 256, 0, stream>>>(vis, Wt, Wg, bt, bg, text,
                                  pooled, WtT_b, cbb, u, t8p);
  matvec8<<<256, 256, 0, stream>>>(Wv, 1024, 0, pooled, bv, vp);  // vp
  prep3<<<512, 256, 0, stream>>>(Wg, Wt, vp, gv, u);              // gv + u
  agwc<<<512, 256, 0, stream>>>(t8p, u, Wg, WtT_b, agr, Wc8p);    // agr + Wc8p
  gemm_ln<<<256, 512, 119296, stream>>>(t8p, text, cbb, agr, gv, vp,
                                        gamma, beta, out);
}